// Round 2
// baseline (173.323 us; speedup 1.0000x reference)
//
#include <hip/hip_runtime.h>

#define PH 7
#define PW 7
#define NB 49
#define SSCALE 0.0625f
#define CC 256
#define HH 200
#define WW 200
#define HWSZ (HH * WW)

#define CPG 8                       // channels per block
#define SROWS 28                    // dedup'd rows: 7ph x 2 samples x {yl,yl+1}
#define NSLOT 11                    // float4 slots per row (44 floats)
#define PITCHF 44
#define CH_T  (SROWS * PITCHF + 4)  // 1236 floats: +4 skew -> ch banks 20*ch mod 32 (8 distinct)
#define NROWS (CPG * SROWS)         // 224 distinct (ch,row) pairs per block
#define RPP   23                    // row-streams per pass: 23 rows x 11 slots = 253 threads
#define NIT   10                    // ceil(NROWS / RPP)

typedef float f4 __attribute__((ext_vector_type(4)));

__global__ __launch_bounds__(256) void roi_align_v9(
    const float* __restrict__ features, const float* __restrict__ rois,
    float* __restrict__ out, int N)
{
    __shared__ float lds[CPG * CH_T];   // 39,552 B
    __shared__ int   tab[NROWS];        // +896 B -> 40,448 B total: still 4 blocks/CU

    // ---- XCD-affinity swizzle: all N rois of one channel-group land on one XCD ----
    // linear wgid round-robins over 8 XCDs -> xcd = L&7. XCD k runs cgroups
    // {k, k+8, k+16, k+24} sequentially; working set per phase = 8ch x 2 batches
    // = 2.56 MB < 4 MB XCD L2.
    const int L     = blockIdx.x;
    const int xcd   = L & 7;
    const int slot  = L >> 3;
    const int phase = slot / N;          // uniform, once per block
    const int n     = slot - phase * N;  // roi index
    const int c0    = ((phase << 3) + xcd) * CPG;

    const int t = threadIdx.x;

    const float* r = rois + (size_t)n * 5;
    const int   b  = (int)r[0];
    const float x1 = r[1] * SSCALE, y1 = r[2] * SSCALE;
    const float x2 = r[3] * SSCALE, y2 = r[4] * SSCALE;
    const float bw = fmaxf(x2 - x1, 1.f) * (1.f / PW);
    const float bh = fmaxf(y2 - y1, 1.f) * (1.f / PH);

    const float xA    = x1 + 0.25f * bw;
    const int   col0  = min((int)fmaxf(xA, 0.f), WW - 1);
    const int   col0a = col0 & ~3;          // float4-aligned window base

    const float* fbase = features + (size_t)(b * CC + c0) * HWSZ;

    // ============ phase 0: per-row geometry table (computed once, not 11x) ============
    // packed: [lds_float_base (14b) << 11 | ch*HH+grow (11b)]
    //   lds_base <= 7*1236 + 27*44 = 9840 < 2^14; q <= 7*200+199 = 1599 < 2^11
    if (t < NROWS) {
        int ch = t / SROWS;                  // magic-mul (const 28), once
        int rr = t - ch * SROWS;
        int s  = rr >> 1;                    // y-sample 0..13
        float sf = (s & 1) ? 0.75f : 0.25f;
        float y  = y1 + ((float)(s >> 1) + sf) * bh;
        int   yl = min((int)fmaxf(y, 0.f), HH - 1);
        int  grow = min(yl + (rr & 1), HH - 1);
        int  q  = ch * HH + grow;            // global row id: goff = q*WW
        int  lb = ch * CH_T + rr * PITCHF;
        tab[t] = (lb << 11) | q;
    }
    __syncthreads();    // barrier #1 (cheap: before any staging work)

    // ============ staging: table-driven, ~5 VALU per load ============
    // thread t owns (slot = t%11, row-stream r0 = t/11); rows advance by 23/pass.
    // Lanes 0..10 cover one contiguous 176B row segment -> coalescing preserved.
    // tab read: lanes 0..10 same addr (broadcast), distinct r0 -> distinct banks.
    const int  slotI = t % NSLOT;            // magic-mul (const 11), once
    const int  r0    = t / NSLOT;
    const bool lact  = (r0 < RPP);           // threads 253..255 idle in staging
    const int  gcol  = min(col0a + (slotI << 2), WW - 4);   // per-thread constant

    f4  v[NIT];
    int la[NIT];
    #pragma unroll
    for (int k = 0; k < NIT; ++k) {
        int rl = r0 + k * RPP;
        bool a = (k == NIT - 1) ? (lact && rl < NROWS) : lact;
        if (a) {
            int w = tab[rl];                 // ds_read_b32, imm offset 92*k
            la[k] = (w >> 11) + (slotI << 2);
            int q = w & 0x7FF;
            v[k]  = *(const f4*)(fbase + q * WW + gcol);
        }
    }
    #pragma unroll
    for (int k = 0; k < NIT; ++k) {
        int rl = r0 + k * RPP;
        bool a = (k == NIT - 1) ? (lact && rl < NROWS) : lact;
        if (a) *(f4*)&lds[la[k]] = v[k];
    }

    // ---- per-thread setup: 1 channel x 2 bins (overlaps staging latency) ----
    const int ch = t & 7;
    const int g  = t >> 3;                 // 0..31
    const int bin0 = g;
    const bool act1 = (g + 32 < NB);       // g <= 16
    const int bin1 = act1 ? (g + 32) : (NB - 1);

    float wy0[2][2], wy1[2][2], wx0[2][2], wx1[2][2];
    int   rb[2][2], oA[2][2];
    #pragma unroll
    for (int j = 0; j < 2; ++j) {
        int bn = j ? bin1 : bin0;
        int ph = bn / PW;                  // magic-mul
        int pw = bn - ph * PW;
        #pragma unroll
        for (int i = 0; i < 2; ++i) {
            float sf = i ? 0.75f : 0.25f;

            float y  = y1 + ((float)ph + sf) * bh;
            bool  vy = (y >= -1.f) && (y <= (float)HH);
            float cy = fmaxf(y, 0.f);
            int   yl = min((int)cy, HH - 1);
            float fy = (yl >= HH - 1) ? 0.f : (cy - (float)yl);
            wy0[j][i] = vy ? (1.f - fy) : 0.f;
            wy1[j][i] = vy ? fy : 0.f;
            rb[j][i]  = (2 * ph + i) * (2 * PITCHF);

            float x  = x1 + ((float)pw + sf) * bw;
            bool  vx = (x >= -1.f) && (x <= (float)WW);
            float cx = fmaxf(x, 0.f);
            int   xl = min((int)cx, WW - 1);
            float fx = (xl >= WW - 1) ? 0.f : (cx - (float)xl);
            wx0[j][i] = vx ? (1.f - fx) : 0.f;
            wx1[j][i] = vx ? fx : 0.f;     // fx==0 at right edge -> p[1] weight 0
            oA[j][i]  = xl - col0a;        // 0..43
        }
    }

    __syncthreads();   // barrier #2

    // ============ compute: immediate-offset tap reads (ds_read2-friendly) ============
    const float* tb = &lds[ch * CH_T];
    float acc0 = 0.f, acc1 = 0.f;
    #pragma unroll
    for (int j = 0; j < 2; ++j) {
        float a = 0.f;
        #pragma unroll
        for (int iy = 0; iy < 2; ++iy) {
            float w0 = wy0[j][iy], w1 = wy1[j][iy];
            #pragma unroll
            for (int ix = 0; ix < 2; ++ix) {
                const float* p = tb + rb[j][iy] + oA[j][ix];
                float hx = wx0[j][ix], lx = wx1[j][ix];
                a += w0 * (hx * p[0]      + lx * p[1])
                   + w1 * (hx * p[PITCHF] + lx * p[PITCHF + 1]);
            }
        }
        if (j == 0) acc0 = a; else acc1 = a;
    }

    float* obase = out + (size_t)(n * CC + c0) * NB + (size_t)ch * NB;
    obase[bin0] = acc0 * 0.25f;
    if (act1) obase[bin1] = acc1 * 0.25f;
}

extern "C" void kernel_launch(void* const* d_in, const int* in_sizes, int n_in,
                              void* d_out, int out_size, void* d_ws, size_t ws_size,
                              hipStream_t stream) {
    const float* features = (const float*)d_in[0];
    const float* rois     = (const float*)d_in[1];
    float*       out      = (float*)d_out;

    int N = in_sizes[1] / 5;            // 512 rois
    int nblk = N * (CC / CPG);          // 16384, multiple of 8 (bijective swizzle)

    roi_align_v9<<<dim3(nblk), 256, 0, stream>>>(features, rois, out, N);
}

// Round 3
// 158.958 us; speedup vs baseline: 1.0904x; 1.0904x over previous
//
#include <hip/hip_runtime.h>

#define PH 7
#define PW 7
#define NB 49
#define SSCALE 0.0625f
#define CC 256
#define HH 200
#define WW 200
#define HWSZ (HH * WW)

#define CPG 8                      // channels per block
#define SROW 14                    // y-interpolated sample rows: 7ph x 2 ysamples
#define NSLOT 11                   // float4 slots per row (44 floats)
#define PITCHF 44
#define CH_T  (SROW * PITCHF + 4)  // 620 floats: +4 zeroed pad so p[oA+1] on s=13 is finite
#define NROWS (CPG * SROW)         // 112 (ch,s) tab entries
#define RSTR  23                   // row-streams: 23 x 11 slots = 253 active threads

typedef float f4 __attribute__((ext_vector_type(4)));

__global__ __launch_bounds__(256, 6) void roi_align_v10(
    const float* __restrict__ features, const float* __restrict__ rois,
    float* __restrict__ out, int N)
{
    __shared__ float lds[CPG * CH_T];   // 19,840 B
    __shared__ int2  tab[NROWS];        // +896 B = 20,736 B -> 6-7 blocks/CU

    // ---- XCD-affinity swizzle (unchanged from v9: FETCH 198->37 MB, keep) ----
    const int L     = blockIdx.x;
    const int xcd   = L & 7;
    const int slot  = L >> 3;
    const int phase = slot / N;          // uniform per block
    const int n     = slot - phase * N;  // roi index
    const int c0    = ((phase << 3) + xcd) * CPG;

    const int t = threadIdx.x;

    const float* r = rois + (size_t)n * 5;
    const int   b  = (int)r[0];
    const float x1 = r[1] * SSCALE, y1 = r[2] * SSCALE;
    const float x2 = r[3] * SSCALE, y2 = r[4] * SSCALE;
    const float bw = fmaxf(x2 - x1, 1.f) * (1.f / PW);
    const float bh = fmaxf(y2 - y1, 1.f) * (1.f / PH);

    const float xA    = x1 + 0.25f * bw;
    const int   col0  = min((int)fmaxf(xA, 0.f), WW - 1);
    const int   col0a = col0 & ~3;          // float4-aligned window base

    const float* fbase = features + (size_t)(b * CC + c0) * HWSZ;

    // ======== tab: per-(ch,s) y-geometry + exact fy bits ========
    // word0 = vy<<25 | inc<<24 | lds_base(13b)<<11 | q1(11b), word1 = bits(fy)
    //   lds_base <= 7*620+13*44 = 4912 < 8192; q1 <= 1599 < 2048
    if (t < NROWS) {
        int ch = t / SROW;                 // magic-mul /14, once
        int s  = t - ch * SROW;
        float sf = (s & 1) ? 0.75f : 0.25f;
        float y  = y1 + ((float)(s >> 1) + sf) * bh;
        bool  vy = (y >= -1.f) && (y <= (float)HH);
        float cy = fmaxf(y, 0.f);
        int   yl = min((int)cy, HH - 1);
        float fy = (yl >= HH - 1) ? 0.f : (cy - (float)yl);
        int  inc = (yl < HH - 1) ? 1 : 0;  // second tap row = yl+inc
        int   q1 = ch * HH + yl;
        int   lb = ch * CH_T + s * PITCHF;
        tab[t] = make_int2((vy ? (1 << 25) : 0) | (inc << 24) | (lb << 11) | q1,
                           __float_as_int(fy));
    }
    if (t >= 128 && t < 160) {             // zero 4-float pad tail of each channel
        int c = (t - 128) >> 2;
        lds[c * CH_T + SROW * PITCHF + (t & 3)] = 0.f;
    }
    __syncthreads();    // barrier #1

    // ======== staging: load BOTH y-tap rows, combine in regs, write ONE row ====
    // thread t owns (slot = t%11, row-stream r0 = t/11); rows advance by 23.
    // Lanes 0..10 cover one contiguous 176B row segment -> coalesced.
    const int  slotI = t % NSLOT;
    const int  r0    = t / NSLOT;
    const bool lact  = (r0 < RSTR);
    const int  gcol  = min(col0a + (slotI << 2), WW - 4);

    f4 va[3], vb[3]; float wA[3], wB[3]; int la[3];

    // batch A: rows r0, r0+23, r0+46 (6 global loads in flight)
    #pragma unroll
    for (int k = 0; k < 3; ++k) {
        if (lact) {
            int2 w  = tab[r0 + k * RSTR];
            int  q1 = w.x & 0x7FF;
            int  inc = (w.x >> 24) & 1;
            bool vy  = (w.x >> 25) & 1;
            float fy = __int_as_float(w.y);
            wB[k] = vy ? fy : 0.f;
            wA[k] = vy ? (1.f - fy) : 0.f;
            la[k] = ((w.x >> 11) & 0x1FFF) + (slotI << 2);
            const float* g1 = fbase + q1 * WW + gcol;
            va[k] = *(const f4*)g1;
            vb[k] = *(const f4*)(g1 + inc * WW);
        }
    }

    // ---- per-thread x-setup: overlaps batch-A latency ----
    const int ch = t & 7;
    const int g  = t >> 3;                 // 0..31
    const int bin0 = g;
    const bool act1 = (g + 32 < NB);
    const int bin1 = act1 ? (g + 32) : (NB - 1);

    float wx0[2][2], wx1[2][2];
    int   rb[2][2], oA[2][2];
    #pragma unroll
    for (int j = 0; j < 2; ++j) {
        int bn = j ? bin1 : bin0;
        int ph = bn / PW;                  // magic-mul
        int pw = bn - ph * PW;
        #pragma unroll
        for (int i = 0; i < 2; ++i) {
            float sf = i ? 0.75f : 0.25f;
            rb[j][i] = (2 * ph + i) * PITCHF;     // y-interp'd sample row s=2ph+i

            float x  = x1 + ((float)pw + sf) * bw;
            bool  vx = (x >= -1.f) && (x <= (float)WW);
            float cx = fmaxf(x, 0.f);
            int   xl = min((int)cx, WW - 1);
            float fx = (xl >= WW - 1) ? 0.f : (cx - (float)xl);
            wx0[j][i] = vx ? (1.f - fx) : 0.f;
            wx1[j][i] = vx ? fx : 0.f;     // fx==0 at right edge -> tap2 weight 0
            oA[j][i]  = xl - col0a;        // 0..43
        }
    }

    // write A (compiler inserts vmcnt waits)
    #pragma unroll
    for (int k = 0; k < 3; ++k)
        if (lact) *(f4*)&lds[la[k]] = wA[k] * va[k] + wB[k] * vb[k];

    // batch B: rows r0+69 (always), r0+92 (if < 112)
    #pragma unroll
    for (int k = 0; k < 2; ++k) {
        int idx = r0 + (k + 3) * RSTR;
        bool a = lact && (k == 0 || idx < NROWS);
        if (a) {
            int2 w  = tab[idx];
            int  q1 = w.x & 0x7FF;
            int  inc = (w.x >> 24) & 1;
            bool vy  = (w.x >> 25) & 1;
            float fy = __int_as_float(w.y);
            wB[k] = vy ? fy : 0.f;
            wA[k] = vy ? (1.f - fy) : 0.f;
            la[k] = ((w.x >> 11) & 0x1FFF) + (slotI << 2);
            const float* g1 = fbase + q1 * WW + gcol;
            va[k] = *(const f4*)g1;
            vb[k] = *(const f4*)(g1 + inc * WW);
        }
    }
    #pragma unroll
    for (int k = 0; k < 2; ++k) {
        int idx = r0 + (k + 3) * RSTR;
        bool a = lact && (k == 0 || idx < NROWS);
        if (a) *(f4*)&lds[la[k]] = wA[k] * va[k] + wB[k] * vb[k];
    }

    __syncthreads();   // barrier #2

    // ======== compute: 8 dword reads per thread (was 16) ========
    const float* tb = &lds[ch * CH_T];
    float acc0 = 0.f, acc1 = 0.f;
    #pragma unroll
    for (int j = 0; j < 2; ++j) {
        float a = 0.f;
        #pragma unroll
        for (int iy = 0; iy < 2; ++iy) {
            const float* p = tb + rb[j][iy];
            #pragma unroll
            for (int ix = 0; ix < 2; ++ix) {
                a += wx0[j][ix] * p[oA[j][ix]] + wx1[j][ix] * p[oA[j][ix] + 1];
            }
        }
        if (j == 0) acc0 = a; else acc1 = a;
    }

    float* obase = out + (size_t)(n * CC + c0) * NB + (size_t)ch * NB;
    obase[bin0] = acc0 * 0.25f;
    if (act1) obase[bin1] = acc1 * 0.25f;
}

extern "C" void kernel_launch(void* const* d_in, const int* in_sizes, int n_in,
                              void* d_out, int out_size, void* d_ws, size_t ws_size,
                              hipStream_t stream) {
    const float* features = (const float*)d_in[0];
    const float* rois     = (const float*)d_in[1];
    float*       out      = (float*)d_out;

    int N = in_sizes[1] / 5;            // 512 rois
    int nblk = N * (CC / CPG);          // 16384, multiple of 8 (bijective swizzle)

    roi_align_v10<<<dim3(nblk), 256, 0, stream>>>(features, rois, out, N);
}

// Round 4
// 154.800 us; speedup vs baseline: 1.1197x; 1.0269x over previous
//
#include <hip/hip_runtime.h>

#define PH 7
#define PW 7
#define NB 49
#define SSCALE 0.0625f
#define CC 256
#define HH 200
#define WW 200
#define HWSZ (HH * WW)

#define CPG 4                     // channels per block = waves per block
#define SROW 14                   // y-interpolated sample rows: 7ph x 2 ysamples
#define NSLOT 11                  // float4 slots per row (44 floats)
#define PITCHF 44
#define CH_T  (SROW * PITCHF + 4) // 620 floats per wave-private region
#define NPAIR (SROW * NSLOT)      // 154 (row,slot) staging pairs per channel

typedef float f4 __attribute__((ext_vector_type(4)));

__global__ __launch_bounds__(256, 8) void roi_align_v11(
    const float* __restrict__ features, const float* __restrict__ rois,
    float* __restrict__ out, int N)
{
    __shared__ float lds[CPG * CH_T];   // 9,920 B -> LDS never the occupancy cap

    // ---- XCD-affinity swizzle: keep (FETCH 198->37 MB in v9/v10) ----
    // 64 cgroups over 8 XCDs x 8 phases; working set/phase = 4ch x 2 batches
    // = 1.28 MB << 4 MB XCD L2.
    const int L     = blockIdx.x;
    const int xcd   = L & 7;
    const int slot  = L >> 3;
    const int phase = slot / N;          // uniform per block
    const int n     = slot - phase * N;  // roi index
    const int c0    = ((phase << 3) + xcd) * CPG;

    const int t    = threadIdx.x;
    const int wid  = t >> 6;
    const int lane = t & 63;

    // roi decode: block-uniform -> scalar loads / SALU
    const float* r = rois + (size_t)n * 5;
    const int   b  = (int)r[0];
    const float x1 = r[1] * SSCALE, y1 = r[2] * SSCALE;
    const float x2 = r[3] * SSCALE, y2 = r[4] * SSCALE;
    const float bw = fmaxf(x2 - x1, 1.f) * (1.f / PW);
    const float bh = fmaxf(y2 - y1, 1.f) * (1.f / PH);

    const float xA    = x1 + 0.25f * bw;
    const int   col0  = min((int)fmaxf(xA, 0.f), WW - 1);
    const int   col0a = col0 & ~3;       // float4-aligned window base

    const int    c     = c0 + wid;       // this wave's channel
    const float* fbase = features + (size_t)(b * CC + c) * HWSZ;
    float*       tb    = &lds[wid * CH_T];   // wave-private region

    // ======== staging: 3 masked passes over 154 (row s, slot) pairs ========
    // pass p, lane l -> idx = l + 64p: s = idx/11, slot = idx%11.
    // Lanes 0..10 cover one contiguous 176B row segment -> coalesced loads.
    // Load BOTH y-tap rows, combine in regs, write ONE y-interp'd row.
    f4 va[3], vb[3]; float wA[3], wB[3]; int la[3]; bool act[3];
    #pragma unroll
    for (int p = 0; p < 3; ++p) {
        int idx = lane + (p << 6);
        act[p] = (p < 2) || (idx < NPAIR);
        if (act[p]) {
            int s  = idx / NSLOT;            // magic-mul /11
            int sl = idx - s * NSLOT;
            float sf = (s & 1) ? 0.75f : 0.25f;
            float y  = y1 + ((float)(s >> 1) + sf) * bh;
            bool  vy = (y >= -1.f) && (y <= (float)HH);
            float cy = fmaxf(y, 0.f);
            int   yl = min((int)cy, HH - 1);
            float fy = (yl >= HH - 1) ? 0.f : (cy - (float)yl);
            int  inc = (yl < HH - 1) ? 1 : 0;
            wA[p] = vy ? (1.f - fy) : 0.f;
            wB[p] = vy ? fy : 0.f;
            int gcol = min(col0a + (sl << 2), WW - 4);
            const float* g1 = fbase + yl * WW + gcol;
            va[p] = *(const f4*)g1;
            vb[p] = *(const f4*)(g1 + inc * WW);
            la[p] = s * PITCHF + (sl << 2);
        }
    }

    // ---- x-setup overlaps load latency (no LDS dependence; index-only,
    //      safe for lanes >= NB since it touches no memory) ----
    int ph = lane / PW;                  // magic-mul /7
    int pw = lane - ph * PW;
    float wx0[2], wx1[2]; int oA[2];
    #pragma unroll
    for (int i = 0; i < 2; ++i) {
        float sf = i ? 0.75f : 0.25f;
        float x  = x1 + ((float)pw + sf) * bw;
        bool  vx = (x >= -1.f) && (x <= (float)WW);
        float cx = fmaxf(x, 0.f);
        int   xl = min((int)cx, WW - 1);
        float fx = (xl >= WW - 1) ? 0.f : (cx - (float)xl);
        wx0[i] = vx ? (1.f - fx) : 0.f;
        wx1[i] = vx ? fx : 0.f;          // fx==0 at right edge -> tap2 weight 0
        oA[i]  = xl - col0a;             // 0..43
    }

    // combine + write (compiler inserts vmcnt before each use)
    #pragma unroll
    for (int p = 0; p < 3; ++p)
        if (act[p]) *(f4*)&tb[la[p]] = wA[p] * va[p] + wB[p] * vb[p];

    // wave-internal sync: all our DS writes complete -> visible to our lanes.
    // No __syncthreads anywhere: waves are fully independent.
    asm volatile("s_waitcnt lgkmcnt(0)" ::: "memory");

    // ======== compute: 1 bin/lane, 4 x ds_read2_b32 + ~12 FMA ========
    if (lane < NB) {
        float a = 0.f;
        #pragma unroll
        for (int iy = 0; iy < 2; ++iy) {
            const float* p = tb + (2 * ph + iy) * PITCHF;
            #pragma unroll
            for (int i = 0; i < 2; ++i)
                a += wx0[i] * p[oA[i]] + wx1[i] * p[oA[i] + 1];
        }
        out[(size_t)(n * CC + c) * NB + lane] = a * 0.25f;  // coalesced 196B/wave
    }
}

extern "C" void kernel_launch(void* const* d_in, const int* in_sizes, int n_in,
                              void* d_out, int out_size, void* d_ws, size_t ws_size,
                              hipStream_t stream) {
    const float* features = (const float*)d_in[0];
    const float* rois     = (const float*)d_in[1];
    float*       out      = (float*)d_out;

    int N = in_sizes[1] / 5;            // 512 rois
    int nblk = N * (CC / CPG);          // 32768, multiple of 8 (bijective swizzle)

    roi_align_v11<<<dim3(nblk), 256, 0, stream>>>(features, rois, out, N);
}

// Round 5
// 152.245 us; speedup vs baseline: 1.1384x; 1.0168x over previous
//
#include <hip/hip_runtime.h>

#define PH 7
#define PW 7
#define NB 49
#define SSCALE 0.0625f
#define CC 256
#define HH 200
#define WW 200
#define HWSZ (HH * WW)

#define CPW 2                     // channels per wave
#define CPG 8                     // channels per block = 4 waves x CPW
#define SROW 14                   // y-interpolated sample rows: 7ph x 2 ysamples
#define NSLOT 11                  // float4 slots per row (44 floats)
#define PITCHF 44
#define CH_T  (SROW * PITCHF + 4) // 620 floats per channel region
#define RSTR  5                   // rowstreams per pass: lanes 0..54 = 5 x 11

typedef float f4 __attribute__((ext_vector_type(4)));

__global__ __launch_bounds__(256, 8) void roi_align_v12(
    const float* __restrict__ features, const float* __restrict__ rois,
    float* __restrict__ out, int N)
{
    __shared__ float lds[CPG * CH_T];   // 19,840 B -> 8 blocks/CU (159.7 KB)

    // ---- XCD-affinity swizzle (kept: FETCH 198->37 MB since v9) ----
    // 32 cgroups over 8 XCDs x 4 phases; per-phase set = 8ch x 2 batches
    // = 2.56 MB < 4 MB XCD L2.
    const int L     = blockIdx.x;
    const int xcd   = L & 7;
    const int slot  = L >> 3;
    const int phase = slot / N;          // uniform per block
    const int n     = slot - phase * N;  // roi index
    const int c0    = ((phase << 3) + xcd) * CPG;

    const int t    = threadIdx.x;
    const int wid  = __builtin_amdgcn_readfirstlane(t >> 6);  // force SGPR
    const int lane = t & 63;

    // roi decode: block-uniform -> scalar loads / SALU
    const float* r = rois + (size_t)n * 5;
    const int   b  = (int)r[0];
    const float x1 = r[1] * SSCALE, y1 = r[2] * SSCALE;
    const float x2 = r[3] * SSCALE, y2 = r[4] * SSCALE;
    const float bw = fmaxf(x2 - x1, 1.f) * (1.f / PW);
    const float bh = fmaxf(y2 - y1, 1.f) * (1.f / PH);

    const float xA    = x1 + 0.25f * bw;
    const int   col0  = min((int)fmaxf(xA, 0.f), WW - 1);
    const int   col0a = col0 & ~3;       // float4-aligned window base

    const int c = c0 + wid * CPW;        // wave's first channel (uniform)
    const float* fb0 = features + (size_t)(b * CC + c) * HWSZ;       // SGPR base
    const float* fb1 = fb0 + HWSZ;                                   // SGPR base
    float*       tb0 = &lds[wid * CPW * CH_T];   // wave-private, 2 x CH_T

    // ---- staging lane map (computed ONCE): sl fixed, rows advance by 5 ----
    const int  sl   = lane % NSLOT;      // magic-mul, once
    const int  r0   = lane / NSLOT;      // 0..5 (lanes 55-63 idle in staging)
    const bool lact = (lane < RSTR * NSLOT);
    const int  gcol = min(col0a + (sl << 2), WW - 4);
    const int  vcol = gcol << 2;         // byte offset within a feature row

    f4 va0[3], vb0[3], va1[3], vb1[3];
    float wA[3], wB[3];
    int   vla[3];

    // geometry + issue loads for pass p (serves BOTH channels)
    #define STAGE_LOAD(p, PRED)                                              \
    {                                                                        \
        bool a_ = lact && (PRED);                                            \
        if (a_) {                                                            \
            int   s  = r0 + (p) * RSTR;                                      \
            float yb = (float)(s >> 1) + ((s & 1) ? 0.75f : 0.25f);          \
            float y  = y1 + yb * bh;                                         \
            bool  vy = (y >= -1.f) && (y <= (float)HH);                      \
            float cy = fmaxf(y, 0.f);                                        \
            int   yl = min((int)cy, HH - 1);                                 \
            float fy = (yl >= HH - 1) ? 0.f : (cy - (float)yl);              \
            int  inc = (yl < HH - 1) ? (WW * 4) : 0;   /* byte row stride */ \
            wA[p] = vy ? (1.f - fy) : 0.f;                                   \
            wB[p] = vy ? fy : 0.f;                                           \
            int off = yl * (WW * 4) + vcol;                                  \
            va0[p] = *(const f4*)((const char*)fb0 + off);                   \
            vb0[p] = *(const f4*)((const char*)fb0 + off + inc);             \
            va1[p] = *(const f4*)((const char*)fb1 + off);                   \
            vb1[p] = *(const f4*)((const char*)fb1 + off + inc);             \
            vla[p] = s * PITCHF + (sl << 2);                                 \
        }                                                                    \
    }

    #define STAGE_WRITE(p, PRED)                                             \
    {                                                                        \
        bool a_ = lact && (PRED);                                            \
        if (a_) {                                                            \
            *(f4*)&tb0[vla[p]]        = wA[p] * va0[p] + wB[p] * vb0[p];     \
            *(f4*)&tb0[CH_T + vla[p]] = wA[p] * va1[p] + wB[p] * vb1[p];     \
        }                                                                    \
    }

    STAGE_LOAD(0, true)
    STAGE_LOAD(1, true)
    STAGE_WRITE(0, true)                 // vmcnt(8): p0 arrived, frees regs
    STAGE_LOAD(2, r0 < SROW - 2 * RSTR)  // rows 10..13: r0 < 4

    // ---- x-setup overlaps p2 latency (index-only, safe for all lanes) ----
    int ph = lane / PW;                  // magic-mul /7
    int pw = lane - ph * PW;
    float wx0[2], wx1[2]; int oA[2];
    #pragma unroll
    for (int i = 0; i < 2; ++i) {
        float sf = i ? 0.75f : 0.25f;
        float x  = x1 + ((float)pw + sf) * bw;
        bool  vx = (x >= -1.f) && (x <= (float)WW);
        float cx = fmaxf(x, 0.f);
        int   xl = min((int)cx, WW - 1);
        float fx = (xl >= WW - 1) ? 0.f : (cx - (float)xl);
        wx0[i] = vx ? (1.f - fx) : 0.f;
        wx1[i] = vx ? fx : 0.f;          // fx==0 at right edge -> tap2 weight 0
        oA[i]  = xl - col0a;             // 0..41
    }

    STAGE_WRITE(1, true)
    STAGE_WRITE(2, r0 < SROW - 2 * RSTR)

    // wave-internal sync: our DS writes complete -> visible to our lanes.
    // No __syncthreads anywhere: waves fully independent.
    asm volatile("s_waitcnt lgkmcnt(0)" ::: "memory");

    // ======== compute: 1 bin/lane x 2 channels ========
    if (lane < NB) {
        float a0 = 0.f, a1 = 0.f;
        #pragma unroll
        for (int iy = 0; iy < 2; ++iy) {
            const float* p0 = tb0 + (2 * ph + iy) * PITCHF;
            const float* p1 = p0 + CH_T;
            #pragma unroll
            for (int i = 0; i < 2; ++i) {
                a0 += wx0[i] * p0[oA[i]] + wx1[i] * p0[oA[i] + 1];
                a1 += wx0[i] * p1[oA[i]] + wx1[i] * p1[oA[i] + 1];
            }
        }
        float* ob = out + (size_t)(n * CC + c) * NB + lane;
        ob[0]  = a0 * 0.25f;             // coalesced 196 B per wave
        ob[NB] = a1 * 0.25f;             // channel c+1, contiguous
    }
}

extern "C" void kernel_launch(void* const* d_in, const int* in_sizes, int n_in,
                              void* d_out, int out_size, void* d_ws, size_t ws_size,
                              hipStream_t stream) {
    const float* features = (const float*)d_in[0];
    const float* rois     = (const float*)d_in[1];
    float*       out      = (float*)d_out;

    int N = in_sizes[1] / 5;            // 512 rois
    int nblk = N * (CC / CPG);          // 16384, multiple of 8 (bijective swizzle)

    roi_align_v12<<<dim3(nblk), 256, 0, stream>>>(features, rois, out, N);
}